// Round 1
// baseline (287.022 us; speedup 1.0000x reference)
//
#include <hip/hip_runtime.h>

namespace {

// cos(2*pi*n/64); sin(2*pi*n/64) = COS64[(n+48)&63]
constexpr float COS64[64] = {
  1.00000000f,  0.99518473f,  0.98078528f,  0.95694034f,
  0.92387953f,  0.88192126f,  0.83146961f,  0.77301045f,
  0.70710678f,  0.63439328f,  0.55557023f,  0.47139674f,
  0.38268343f,  0.29028468f,  0.19509032f,  0.09801714f,
  0.00000000f, -0.09801714f, -0.19509032f, -0.29028468f,
 -0.38268343f, -0.47139674f, -0.55557023f, -0.63439328f,
 -0.70710678f, -0.77301045f, -0.83146961f, -0.88192126f,
 -0.92387953f, -0.95694034f, -0.98078528f, -0.99518473f,
 -1.00000000f, -0.99518473f, -0.98078528f, -0.95694034f,
 -0.92387953f, -0.88192126f, -0.83146961f, -0.77301045f,
 -0.70710678f, -0.63439328f, -0.55557023f, -0.47139674f,
 -0.38268343f, -0.29028468f, -0.19509032f, -0.09801714f,
 -0.00000000f,  0.09801714f,  0.19509032f,  0.29028468f,
  0.38268343f,  0.47139674f,  0.55557023f,  0.63439328f,
  0.70710678f,  0.77301045f,  0.83146961f,  0.88192126f,
  0.92387953f,  0.95694034f,  0.98078528f,  0.99518473f };

constexpr float TWOPI_64 = 0.09817477042468103f; // 2*pi/64
constexpr int MM = 144;   // 16 ky * 9 kz
constexpr int GD = 2304;  // 16 kx * 144

// ---------------------------------------------------------------------------
// K1: per (b,c,h) slice: z-DFT (9 modes) then w-DFT (16 modes)
//     x[slice][w][d] -> buf1[slice][ky*9+kz] (complex)
// ---------------------------------------------------------------------------
__global__ __launch_bounds__(256) void k1_fwd(const float* __restrict__ x,
                                              float2* __restrict__ buf1) {
  constexpr int AS = 67;               // padded stride (conflict-free)
  __shared__ float2 As[9 * AS];        // A[kz][w]
  const int tid = threadIdx.x;
  const int slice = blockIdx.x;        // bc*64 + h
  const int w = tid >> 2, q = tid & 3;

  // each thread owns one 64B line: x[w][16q .. 16q+15]
  const float4* xp = (const float4*)(x + ((size_t)slice << 12));
  float4 a0 = xp[tid * 4 + 0];
  float4 a1 = xp[tid * 4 + 1];
  float4 a2 = xp[tid * 4 + 2];
  float4 a3 = xp[tid * 4 + 3];
  float xv[16] = {a0.x, a0.y, a0.z, a0.w, a1.x, a1.y, a1.z, a1.w,
                  a2.x, a2.y, a2.z, a2.w, a3.x, a3.y, a3.z, a3.w};

  // partial z-DFT with compile-time twiddles: sum_j xv[j] e^{-2pi i kz j/64}
  float ar[9], ai[9];
#pragma unroll
  for (int kz = 0; kz < 9; ++kz) { ar[kz] = 0.f; ai[kz] = 0.f; }
#pragma unroll
  for (int j = 0; j < 16; ++j) {
    const float v = xv[j];
#pragma unroll
    for (int kz = 0; kz < 9; ++kz) {
      const int n = (kz * j) & 63;
      ar[kz] = fmaf(v, COS64[n], ar[kz]);
      ai[kz] = fmaf(v, -COS64[(n + 48) & 63], ai[kz]);
    }
  }
  // rotate by (-i)^{(q*kz)&3} (the e^{-2pi i kz 16q/64} factor), reduce over q
#pragma unroll
  for (int kz = 0; kz < 9; ++kz) {
    const int m = (q * kz) & 3;
    const float a = ar[kz], b = ai[kz];
    float r  = (m & 1) ? b : a;
    float i2 = (m & 1) ? a : b;
    r  = (m >= 2) ? -r : r;
    i2 = (m == 1 || m == 2) ? -i2 : i2;
    r  += __shfl_xor(r, 1);  r  += __shfl_xor(r, 2);
    i2 += __shfl_xor(i2, 1); i2 += __shfl_xor(i2, 2);
    if (q == 0) As[kz * AS + w] = make_float2(r, i2);
  }
  __syncthreads();

  // w-DFT: B[ky][kz] = sum_w A[kz][w] e^{-2pi i ky w/64}  (phase recurrence)
  if (tid < MM) {
    const int ky = tid / 9, kz = tid - ky * 9;
    float sn, cs;
    sincosf(TWOPI_64 * (float)ky, &sn, &cs);   // step = (cs, -sn)
    float px = 1.f, py = 0.f, br = 0.f, bi = 0.f;
    for (int ww = 0; ww < 64; ++ww) {
      const float2 a = As[kz * AS + ww];
      br = fmaf(a.x, px, fmaf(-a.y, py, br));
      bi = fmaf(a.x, py, fmaf( a.y, px, bi));
      const float nx = fmaf(px, cs,  py * sn);
      const float ny = fmaf(py, cs, -px * sn);
      px = nx; py = ny;
    }
    buf1[(size_t)slice * MM + tid] = make_float2(br, bi);
  }
}

// ---------------------------------------------------------------------------
// K2: h-DFT: S[bc][kx][m] = sum_h buf1[bc][h][m] e^{-2pi i kx h/64}
// ---------------------------------------------------------------------------
__global__ __launch_bounds__(256) void k2_fwd(const float2* __restrict__ buf1,
                                              float2* __restrict__ buf2) {
  __shared__ float2 Bs[32 * MM];       // half of the h range at a time
  const int tid = threadIdx.x, bc = blockIdx.x;
  const float2* src = buf1 + (size_t)bc * 64 * MM;
  float accr[16], acci[16];
#pragma unroll
  for (int kx = 0; kx < 16; ++kx) { accr[kx] = 0.f; acci[kx] = 0.f; }
  const float bcc = COS64[1];          // cos(2pi/64)
  const float bss = -COS64[49];        // -sin(2pi/64): step = e^{-2pi i/64}
  float phx = 1.f, phy = 0.f;          // e^{-2pi i h/64}
  for (int c2 = 0; c2 < 2; ++c2) {
    for (int i = tid; i < 32 * MM; i += 256) Bs[i] = src[c2 * 32 * MM + i];
    __syncthreads();
    if (tid < MM) {
      for (int hh = 0; hh < 32; ++hh) {
        const float2 v = Bs[hh * MM + tid];
        float pkx = 1.f, pky = 0.f;    // e^{-2pi i kx h/64}
#pragma unroll
        for (int kx = 0; kx < 16; ++kx) {
          accr[kx] = fmaf(v.x, pkx, fmaf(-v.y, pky, accr[kx]));
          acci[kx] = fmaf(v.x, pky, fmaf( v.y, pkx, acci[kx]));
          const float nx = fmaf(pkx, phx, -pky * phy);
          const float ny = fmaf(pkx, phy,  pky * phx);
          pkx = nx; pky = ny;
        }
        const float nx = fmaf(phx, bcc, -phy * bss);
        const float ny = fmaf(phx, bss,  phy * bcc);
        phx = nx; phy = ny;
      }
    }
    __syncthreads();
  }
  if (tid < MM) {
#pragma unroll
    for (int kx = 0; kx < 16; ++kx)
      buf2[(size_t)bc * GD + kx * MM + tid] = make_float2(accr[kx], acci[kx]);
  }
}

// ---------------------------------------------------------------------------
// K3: gate MLP. pooled[b][c] = S_DC.re / 64^3. Writes g-1.
// ---------------------------------------------------------------------------
__global__ __launch_bounds__(256) void k3_gates(const float2* __restrict__ buf2,
    const float* __restrict__ w1, const float* __restrict__ b1,
    const float* __restrict__ w2, const float* __restrict__ b2,
    float* __restrict__ gm1) {
  __shared__ float pooled[64];
  __shared__ float hs[16];
  const int b = blockIdx.x, tid = threadIdx.x;
  if (tid < 64)
    pooled[tid] = buf2[(size_t)(b * 64 + tid) * GD].x * (1.f / 262144.f);
  __syncthreads();
  if (tid < 16) {
    float acc = b1[tid];
    for (int c = 0; c < 64; ++c) acc = fmaf(pooled[c], w1[c * 16 + tid], acc);
    hs[tid] = fmaxf(acc, 0.f);
  }
  __syncthreads();
#pragma unroll
  for (int r = 0; r < 9; ++r) {
    const int o = tid + r * 256;
    float acc = b2[o];
#pragma unroll
    for (int j = 0; j < 16; ++j) acc = fmaf(hs[j], w2[j * GD + o], acc);
    gm1[b * GD + o] = 1.f / (1.f + expf(-acc)) - 1.f;
  }
}

// ---------------------------------------------------------------------------
// K4_scale: D = (g-1) * S, in place in buf2.
// ---------------------------------------------------------------------------
__global__ __launch_bounds__(256) void k4_scale(float2* buf2,
                                                const float* __restrict__ gm1) {
  const int bc = blockIdx.x, tid = threadIdx.x, b = bc >> 6;
#pragma unroll
  for (int r = 0; r < 9; ++r) {
    const int o = tid + r * 256;
    const float g = gm1[b * GD + o];
    const float2 v = buf2[(size_t)bc * GD + o];
    buf2[(size_t)bc * GD + o] = make_float2(v.x * g, v.y * g);
  }
}

// ---------------------------------------------------------------------------
// K4b: inverse synthesis per slice + out = x + delta/64^3
// ---------------------------------------------------------------------------
__global__ __launch_bounds__(256) void k4b_final(const float2* __restrict__ D,
                                                 const float* __restrict__ x,
                                                 float* __restrict__ out) {
  __shared__ float2 C1s[MM];
  __shared__ float2 C2s[9 * 65];       // C2[kz][w], padded
  const int tid = threadIdx.x, slice = blockIdx.x;
  const int bc = slice >> 6, h = slice & 63;

  // C1[m] = sum_kx D[bc][kx][m] e^{+2pi i kx h/64}
  if (tid < MM) {
    const float2* Dp = D + (size_t)bc * GD + tid;
    float sn, cs;
    sincosf(TWOPI_64 * (float)h, &sn, &cs);   // step = (cs, sn) = e^{+2pi i h/64}
    float px = 1.f, py = 0.f, ar = 0.f, ai = 0.f;
#pragma unroll
    for (int kx = 0; kx < 16; ++kx) {
      const float2 dv = Dp[kx * MM];
      ar = fmaf(dv.x, px, fmaf(-dv.y, py, ar));
      ai = fmaf(dv.x, py, fmaf( dv.y, px, ai));
      const float nx = fmaf(px, cs, -py * sn);
      const float ny = fmaf(px, sn,  py * cs);
      px = nx; py = ny;
    }
    C1s[tid] = make_float2(ar, ai);
  }
  __syncthreads();

  // C2[kz][w] = sum_ky C1[ky*9+kz] e^{+2pi i ky w/64}; thread (w,q) does kz set
  {
    const int w = tid >> 2, q = tid & 3;
    float sn, cs;
    sincosf(TWOPI_64 * (float)w, &sn, &cs);   // step = e^{+2pi i w/64}
    const int kz0 = q, kz1 = q + 4;           // q==0 also does kz=8
    float a0r = 0.f, a0i = 0.f, a1r = 0.f, a1i = 0.f, a2r = 0.f, a2i = 0.f;
    float px = 1.f, py = 0.f;
    for (int ky = 0; ky < 16; ++ky) {
      const float2 c0 = C1s[ky * 9 + kz0];
      const float2 c1 = C1s[ky * 9 + kz1];
      a0r = fmaf(c0.x, px, fmaf(-c0.y, py, a0r));
      a0i = fmaf(c0.x, py, fmaf( c0.y, px, a0i));
      a1r = fmaf(c1.x, px, fmaf(-c1.y, py, a1r));
      a1i = fmaf(c1.x, py, fmaf( c1.y, px, a1i));
      if (q == 0) {
        const float2 c2v = C1s[ky * 9 + 8];
        a2r = fmaf(c2v.x, px, fmaf(-c2v.y, py, a2r));
        a2i = fmaf(c2v.x, py, fmaf( c2v.y, px, a2i));
      }
      const float nx = fmaf(px, cs, -py * sn);
      const float ny = fmaf(px, sn,  py * cs);
      px = nx; py = ny;
    }
    C2s[kz0 * 65 + w] = make_float2(a0r, a0i);
    C2s[kz1 * 65 + w] = make_float2(a1r, a1i);
    if (q == 0) C2s[8 * 65 + w] = make_float2(a2r, a2i);
  }
  __syncthreads();

  // delta[w][d] = Re(C2[0]) + 2*sum_{kz>=1} Re(C2[kz] e^{+2pi i kz d/64});
  // d = 16q + j: e^{+2pi i kz d/64} = i^{kz q} * e^{+2pi i kz j/64}
  {
    const int w = tid >> 2, q = tid & 3;
    float cr[9], ci[9];
#pragma unroll
    for (int kz = 0; kz < 9; ++kz) {
      const float2 v = C2s[kz * 65 + w];
      const int m = (kz * q) & 3;                 // multiply by i^m
      const float a = v.x, b = v.y;
      float r  = (m & 1) ? b : a;
      float i2 = (m & 1) ? a : b;
      r  = (m == 1 || m == 2) ? -r : r;
      i2 = (m >= 2) ? -i2 : i2;
      cr[kz] = r; ci[kz] = i2;
    }
    float acc[16];
#pragma unroll
    for (int j = 0; j < 16; ++j) acc[j] = cr[0];
#pragma unroll
    for (int kz = 1; kz < 9; ++kz) {
#pragma unroll
      for (int j = 0; j < 16; ++j) {
        const int n = (kz * j) & 63;
        acc[j] = fmaf(cr[kz],  2.f * COS64[n], acc[j]);
        acc[j] = fmaf(ci[kz], -2.f * COS64[(n + 48) & 63], acc[j]);
      }
    }
    const float* xbase = x + ((size_t)slice << 12) + w * 64 + q * 16;
    float* obase = out + ((size_t)slice << 12) + w * 64 + q * 16;
    const float4* xp = (const float4*)xbase;
    float4* op = (float4*)obase;
    const float scale = 1.f / 262144.f;
#pragma unroll
    for (int k = 0; k < 4; ++k) {
      float4 v = xp[k];
      v.x += acc[k * 4 + 0] * scale;
      v.y += acc[k * 4 + 1] * scale;
      v.z += acc[k * 4 + 2] * scale;
      v.w += acc[k * 4 + 3] * scale;
      op[k] = v;
    }
  }
}

} // namespace

extern "C" void kernel_launch(void* const* d_in, const int* in_sizes, int n_in,
                              void* d_out, int out_size, void* d_ws, size_t ws_size,
                              hipStream_t stream) {
  (void)in_sizes; (void)n_in; (void)out_size; (void)ws_size;
  const float* x  = (const float*)d_in[0];
  const float* w1 = (const float*)d_in[1];
  const float* b1 = (const float*)d_in[2];
  const float* w2 = (const float*)d_in[3];
  const float* b2 = (const float*)d_in[4];
  float* out = (float*)d_out;

  char* ws = (char*)d_ws;
  float2* buf1 = (float2*)ws;                                  // 16384*144*8  = 18,874,368 B
  float2* buf2 = (float2*)(ws + 18874368);                     // 256*2304*8   =  4,718,592 B
  float*  gm1  = (float*)(ws + 18874368 + 4718592);            // 4*2304*4     =     36,864 B

  hipLaunchKernelGGL(k1_fwd,   dim3(16384), dim3(256), 0, stream, x, buf1);
  hipLaunchKernelGGL(k2_fwd,   dim3(256),   dim3(256), 0, stream, buf1, buf2);
  hipLaunchKernelGGL(k3_gates, dim3(4),     dim3(256), 0, stream, buf2, w1, b1, w2, b2, gm1);
  hipLaunchKernelGGL(k4_scale, dim3(256),   dim3(256), 0, stream, buf2, gm1);
  hipLaunchKernelGGL(k4b_final,dim3(16384), dim3(256), 0, stream, buf2, x, out);
}